// Round 5
// baseline (337.177 us; speedup 1.0000x reference)
//
#include <hip/hip_runtime.h>
#include <math.h>

#define DD   128      // hidden dim
#define LL   32       // sequence length
#define MS   16       // sequences per block -> grid 512 -> 2 blocks/CU
#define NW   8        // waves per block (merged role: x-GEMM + h-GEMM + gates)
#define NT   512      // 8 waves
#define NSEQ 8192     // B*S
#define XP   136      // x/h LDS row pitch in ushorts (272 B, 16B-aligned)
#define OLP  36       // outl pitch in floats

typedef short bf16x8 __attribute__((ext_vector_type(8)));   // 8 bf16 = 4 VGPRs
typedef float f32x4  __attribute__((ext_vector_type(4)));

// Transposed orientation: A = weights (row = gate-dim), B = x/h (col = seq).
// C has col(lane&15)=seq, row((lane>>4)*4+i)=dim. All lane maps proven r2.
#define MFMA __builtin_amdgcn_mfma_f32_16x16x32_bf16

__device__ __forceinline__ unsigned short f2bf(float f) {
    unsigned u = __float_as_uint(f);
    u += 0x7fffu + ((u >> 16) & 1u);          // round-to-nearest-even
    return (unsigned short)(u >> 16);
}

#if __has_builtin(__builtin_amdgcn_cvt_pk_bf16_f32)
typedef __bf16 bf16x2_t __attribute__((ext_vector_type(2)));
__device__ __forceinline__ unsigned pack2(float a, float b) {
    union { bf16x2_t v; unsigned u; } c;
    c.v = __builtin_amdgcn_cvt_pk_bf16_f32(a, b);
    return c.u;
}
#else
__device__ __forceinline__ unsigned pack2(float a, float b) {
    return (unsigned)f2bf(a) | ((unsigned)f2bf(b) << 16);
}
#endif

__device__ __forceinline__ void pack4(float4 a, unsigned short* dst) {
    union { unsigned u[2]; unsigned long long ull; } pk;
    pk.u[0] = pack2(a.x, a.y);
    pk.u[1] = pack2(a.z, a.w);
    *(unsigned long long*)dst = pk.ull;
}

__device__ __forceinline__ float fast_rcp(float x) {
    return __builtin_amdgcn_rcpf(x);   // v_rcp_f32, ~1 ulp — fine at bf16 output
}

// ---------------------------------------------------------------------------
// Prep: swizzle W_ih / W_hh into per-gate MFMA fragments, bf16. (unchanged)
// Frag index F = ((side*3 + g)*8 + sl)*4 + kk   (side 0=W_ih, 1=W_hh;
// g 0=r,1=z,2=n; sl = 16-dim slice 0..7; kk = K-subtile 0..3).
// Element j of lane (n=lane&15, q=lane>>4):
//   W_side[(g*128 + sl*16 + n) * 128 + (kk*32 + q*8 + j)]
// ---------------------------------------------------------------------------
__global__ void prep_weights(const float* __restrict__ Wih,
                             const float* __restrict__ Whh,
                             unsigned short* __restrict__ Wfrag) {
    int idx  = blockIdx.x * blockDim.x + threadIdx.x;   // 0 .. 98303
    int j    = idx & 7;
    int lane = (idx >> 3) & 63;
    int kk   = (idx >> 9) & 3;
    int sl   = (idx >> 11) & 7;
    int sg   = idx >> 14;            // 0..5 = side*3 + g
    int n = lane & 15, q = lane >> 4;
    int k  = kk * 32 + q * 8 + j;
    int g  = (sg >= 3) ? sg - 3 : sg;
    int gd = g * 128 + sl * 16 + n;
    const float* src = (sg >= 3) ? Whh : Wih;
    Wfrag[idx] = f2bf(src[gd * 128 + k]);
}

// ---------------------------------------------------------------------------
// Merged-role GRU, 2 independent barrier domains per CU:
// Each of 8 waves owns ONE 16-dim gate slice (all 3 gates) and does the
// x-side GEMM, h-side GEMM, gate math, and h-write itself — gx never
// touches LDS (fragments stay in the accumulator). MS=16 -> grid 512 ->
// 2 blocks/CU whose barriers are independent: one block's LDS/MFMA/VALU
// phases fill the other's stalls.
// Weights: 24 frags = 96 VGPR/wave. Biases + w_out live in a small LDS
// table (broadcast reads) to stay under the 128-VGPR/4-waves-per-EU cap.
// Out-projection: per-lane 4-FMA partial dot on f32 h + 2 shuffle-reduce +
// cross-wave sum via a tiny LDS partial buffer (no MFMA, no wofl).
// TRIPWIRE: if FETCH_SIZE >> 68 MB, the 128 cap spilled (r3 failure mode).
// ---------------------------------------------------------------------------
__global__ __launch_bounds__(NT, 4) void gru_mfma(
    const float* __restrict__ x,      // [8192][32][128]
    const float* __restrict__ h0,     // [8192][128]
    const unsigned short* __restrict__ Wfrag,
    const float* __restrict__ b_ih,   // [384]
    const float* __restrict__ b_hh,   // [384]
    const float* __restrict__ w_out,  // [128]
    const float* __restrict__ b_out,  // [1]
    float* __restrict__ out)          // [8192][32]
{
    __shared__ __align__(16) unsigned short xhx[2][MS][XP];  // x bf16 ring
    __shared__ __align__(16) unsigned short xhh[2][MS][XP];  // h bf16 ring
    __shared__ __align__(16) float bt[5][DD];  // 0:br 1:bz 2:bnx 3:bnh 4:wout
    __shared__ __align__(16) float Pp[2][NW][16];            // out partials
    __shared__ __align__(16) float outl[MS][OLP];

    const int tid  = threadIdx.x;
    const int n0   = blockIdx.x * MS;
    const int wv   = tid >> 6;       // 0..7 = dim-slice
    const int lane = tid & 63;
    const int ln   = lane & 15;      // C col = seq
    const int q    = lane >> 4;      // C rows q*4..q*4+3 = dims
    const int d4   = wv * 16 + q * 4;
    const float bo = b_out[0];
    const bf16x8* W = (const bf16x8*)Wfrag;

    // 24 persistent weight fragments (96 VGPR)
    bf16x8 wxr[4], wxz[4], wxn[4], whr[4], whz[4], whn[4];
    #pragma unroll
    for (int kk = 0; kk < 4; ++kk) {
        wxr[kk] = W[((0  + wv)*4 + kk)*64 + lane];
        wxz[kk] = W[((8  + wv)*4 + kk)*64 + lane];
        wxn[kk] = W[((16 + wv)*4 + kk)*64 + lane];
        whr[kk] = W[((24 + wv)*4 + kk)*64 + lane];
        whz[kk] = W[((32 + wv)*4 + kk)*64 + lane];
        whn[kk] = W[((40 + wv)*4 + kk)*64 + lane];
    }

    // bias / w_out table
    if (tid < DD) {
        const int d = tid;
        bt[0][d] = b_ih[d]        + b_hh[d];
        bt[1][d] = b_ih[DD + d]   + b_hh[DD + d];
        bt[2][d] = b_ih[2*DD + d];
        bt[3][d] = b_hh[2*DD + d];
        bt[4][d] = w_out[d];
    }

    // stage h0 -> xhh[0], x_0 -> xhx[0]  (512 threads x 4 f32 = 16x128)
    const int gn  = tid >> 5;            // seq 0..15
    const int gd4 = (tid & 31) * 4;      // dim 0,4,..,124
    pack4(*(const float4*)&h0[(size_t)(n0 + gn) * DD + gd4], &xhh[0][gn][gd4]);
    const float* xbase = x + ((size_t)(n0 + gn) * LL) * DD + gd4;
    pack4(*(const float4*)xbase, &xhx[0][gn][gd4]);

    // fp32 hidden state: lane=seq(ln), regs = dims d4..d4+3
    float4 hp = *(const float4*)&h0[(size_t)(n0 + ln) * DD + d4];
    float hprev[4] = {hp.x, hp.y, hp.z, hp.w};

    __syncthreads();   // #1: staging done

    for (int t = 0; t < LL; ++t) {
        const int cur = t & 1;
        // prefetch x_{t+1} (latency hides under MFMA + gate phases)
        float4 xa;
        if (t + 1 < LL) xa = *(const float4*)(xbase + (size_t)(t + 1) * DD);

        // accumulators init from bias table (broadcast ds_reads)
        f32x4 ar  = *(const f32x4*)&bt[0][d4];
        f32x4 az  = *(const f32x4*)&bt[1][d4];
        f32x4 anx = *(const f32x4*)&bt[2][d4];
        f32x4 anh = *(const f32x4*)&bt[3][d4];

        const unsigned short* xr = &xhx[cur][ln][0];
        const unsigned short* hr = &xhh[cur][ln][0];
        __builtin_amdgcn_s_setprio(1);
        #pragma unroll
        for (int kk = 0; kk < 4; ++kk) {           // x-side, K=128
            bf16x8 bx = *(const bf16x8*)(xr + kk*32 + q*8);
            ar  = MFMA(wxr[kk], bx, ar , 0,0,0);
            az  = MFMA(wxz[kk], bx, az , 0,0,0);
            anx = MFMA(wxn[kk], bx, anx, 0,0,0);
        }
        #pragma unroll
        for (int kk = 0; kk < 4; ++kk) {           // h-side, K=128
            bf16x8 bh = *(const bf16x8*)(hr + kk*32 + q*8);
            ar  = MFMA(whr[kk], bh, ar , 0,0,0);
            az  = MFMA(whz[kk], bh, az , 0,0,0);
            anh = MFMA(whn[kk], bh, anh, 0,0,0);
        }
        __builtin_amdgcn_s_setprio(0);

        // assemble out[t-1] from last step's partials (wave 7 only)
        if (wv == 7 && t >= 1 && lane < 16) {
            float o = bo;
            #pragma unroll
            for (int w = 0; w < NW; ++w) o += Pp[cur ^ 1][w][lane];
            outl[lane][t - 1] = o;
        }

        // gate math (independent chains, r2-proven form)
        float hh_[4];
        #pragma unroll
        for (int i = 0; i < 4; ++i) {
            const float rr = fast_rcp(1.f + __expf(-ar[i]));
            const float zz = fast_rcp(1.f + __expf(-az[i]));
            const float aa = __builtin_fmaf(rr, anh[i], anx[i]);
            const float ee = __expf(-2.f * aa);              // tanh, NaN-free
            const float th = 2.f * fast_rcp(1.f + ee) - 1.f;
            const float hh = __builtin_fmaf(zz, hprev[i] - th, th);
            hprev[i] = hh;
            hh_[i] = hh;
        }
        // h_t write (bf16, vectorized b64)
        {
            union { unsigned u[2]; unsigned long long ull; } hv;
            hv.u[0] = pack2(hh_[0], hh_[1]);
            hv.u[1] = pack2(hh_[2], hh_[3]);
            *(unsigned long long*)&xhh[cur ^ 1][ln][d4] = hv.ull;
        }
        // out partial: f32 dot over this lane's 4 dims, reduce over q
        {
            f32x4 wo = *(const f32x4*)&bt[4][d4];
            float p = hh_[0]*wo[0] + hh_[1]*wo[1] + hh_[2]*wo[2] + hh_[3]*wo[3];
            p += __shfl_xor(p, 16);
            p += __shfl_xor(p, 32);
            if (lane < 16) Pp[cur][wv][lane] = p;
        }
        // stage x_{t+1} into the slot read next iter (WAR-safe: that slot
        // was last read at iter t-1, separated by the iter-(t-1) barrier)
        if (t + 1 < LL) pack4(xa, &xhx[cur ^ 1][gn][gd4]);

        __syncthreads();   // per-step barrier (#2..#33)
    }

    // out[31] from Pp[(LL-1)&1] = Pp[1]
    if (wv == 7 && lane < 16) {
        float o = bo;
        #pragma unroll
        for (int w = 0; w < NW; ++w) o += Pp[1][w][lane];
        outl[lane][LL - 1] = o;
    }
    __syncthreads();       // #34: outl complete

    // coalesced flush: block's 16x32 outputs are contiguous in global
    if (tid < 128) {
        const int row = tid >> 3;
        const int t4  = (tid & 7) * 4;
        float4 v = *(const float4*)&outl[row][t4];
        *(float4*)(out + (size_t)(n0 + row) * LL + t4) = v;
    }
}

extern "C" void kernel_launch(void* const* d_in, const int* in_sizes, int n_in,
                              void* d_out, int out_size, void* d_ws, size_t ws_size,
                              hipStream_t stream) {
    const float* item  = (const float*)d_in[0];
    const float* user  = (const float*)d_in[1];
    const float* W_ih  = (const float*)d_in[2];
    const float* W_hh  = (const float*)d_in[3];
    const float* b_ih  = (const float*)d_in[4];
    const float* b_hh  = (const float*)d_in[5];
    const float* W_out = (const float*)d_in[6];
    const float* b_out = (const float*)d_in[7];
    float* out = (float*)d_out;

    unsigned short* Wfrag = (unsigned short*)d_ws;   // 192 frags * 512 = 98304 bf16

    prep_weights<<<384, 256, 0, stream>>>(W_ih, W_hh, Wfrag);
    gru_mfma<<<NSEQ / MS, NT, 0, stream>>>(item, user, Wfrag,
                                           b_ih, b_hh, W_out, b_out, out);
}

// Round 6
// 292.727 us; speedup vs baseline: 1.1518x; 1.1518x over previous
//
#include <hip/hip_runtime.h>
#include <math.h>

#define DD   128      // hidden dim
#define LL   32       // sequence length
#define MS   16       // sequences per block -> grid 512 -> 2 blocks/CU
#define NW   8        // waves per block (merged role: x-GEMM + h-GEMM + gates)
#define NT   512      // 8 waves
#define NSEQ 8192     // B*S
#define XP   136      // x/h LDS row pitch in ushorts (272 B, 16B-aligned)
#define OLP  36       // outl pitch in floats

typedef short bf16x8 __attribute__((ext_vector_type(8)));   // 8 bf16 = 4 VGPRs
typedef float f32x4  __attribute__((ext_vector_type(4)));

// Transposed orientation: A = weights (row = gate-dim), B = x/h (col = seq).
// C has col(lane&15)=seq, row((lane>>4)*4+i)=dim. All lane maps proven r2/r5.
#define MFMA __builtin_amdgcn_mfma_f32_16x16x32_bf16

__device__ __forceinline__ unsigned short f2bf(float f) {
    unsigned u = __float_as_uint(f);
    u += 0x7fffu + ((u >> 16) & 1u);          // round-to-nearest-even
    return (unsigned short)(u >> 16);
}

#if __has_builtin(__builtin_amdgcn_cvt_pk_bf16_f32)
typedef __bf16 bf16x2_t __attribute__((ext_vector_type(2)));
__device__ __forceinline__ unsigned pack2(float a, float b) {
    union { bf16x2_t v; unsigned u; } c;
    c.v = __builtin_amdgcn_cvt_pk_bf16_f32(a, b);
    return c.u;
}
#else
__device__ __forceinline__ unsigned pack2(float a, float b) {
    return (unsigned)f2bf(a) | ((unsigned)f2bf(b) << 16);
}
#endif

__device__ __forceinline__ void pack4(float4 a, unsigned short* dst) {
    union { unsigned u[2]; unsigned long long ull; } pk;
    pk.u[0] = pack2(a.x, a.y);
    pk.u[1] = pack2(a.z, a.w);
    *(unsigned long long*)dst = pk.ull;
}

__device__ __forceinline__ float fast_rcp(float x) {
    return __builtin_amdgcn_rcpf(x);   // v_rcp_f32, ~1 ulp — fine at bf16 output
}

// ---------------------------------------------------------------------------
// Prep: swizzle W_ih / W_hh into per-gate MFMA fragments, bf16. (unchanged)
// Frag index F = ((side*3 + g)*8 + sl)*4 + kk   (side 0=W_ih, 1=W_hh;
// g 0=r,1=z,2=n; sl = 16-dim slice 0..7; kk = K-subtile 0..3).
// Element j of lane (n=lane&15, q=lane>>4):
//   W_side[(g*128 + sl*16 + n) * 128 + (kk*32 + q*8 + j)]
// ---------------------------------------------------------------------------
__global__ void prep_weights(const float* __restrict__ Wih,
                             const float* __restrict__ Whh,
                             unsigned short* __restrict__ Wfrag) {
    int idx  = blockIdx.x * blockDim.x + threadIdx.x;   // 0 .. 98303
    int j    = idx & 7;
    int lane = (idx >> 3) & 63;
    int kk   = (idx >> 9) & 3;
    int sl   = (idx >> 11) & 7;
    int sg   = idx >> 14;            // 0..5 = side*3 + g
    int n = lane & 15, q = lane >> 4;
    int k  = kk * 32 + q * 8 + j;
    int g  = (sg >= 3) ? sg - 3 : sg;
    int gd = g * 128 + sl * 16 + n;
    const float* src = (sg >= 3) ? Whh : Wih;
    Wfrag[idx] = f2bf(src[gd * 128 + k]);
}

// ---------------------------------------------------------------------------
// Merged-role GRU, 2 independent barrier domains per CU (r5 structure).
// r5 spilled ~12 regs (demand ~140 vs 128 cap) -> 390MB scratch FETCH.
// r6 change: the n-gate x-side weight frags (wxn, 16 VGPRs) move to a
// per-block LDS copy (32KB, staged once, conflict-free lane-linear reads)
// -> register demand ~124 <= 128. Everything else identical to the
// correctness-proven r5 kernel.
// TRIPWIRE: if FETCH_SIZE >> 68 MB, the cap spilled again -> revert.
// ---------------------------------------------------------------------------
__global__ __launch_bounds__(NT, 4) void gru_mfma(
    const float* __restrict__ x,      // [8192][32][128]
    const float* __restrict__ h0,     // [8192][128]
    const unsigned short* __restrict__ Wfrag,
    const float* __restrict__ b_ih,   // [384]
    const float* __restrict__ b_hh,   // [384]
    const float* __restrict__ w_out,  // [128]
    const float* __restrict__ b_out,  // [1]
    float* __restrict__ out)          // [8192][32]
{
    __shared__ __align__(16) unsigned short xhx[2][MS][XP];  // x bf16 ring
    __shared__ __align__(16) unsigned short xhh[2][MS][XP];  // h bf16 ring
    __shared__ __align__(16) unsigned short wnl[2048 * 8];   // wxn frags, 32KB
    __shared__ __align__(16) float bt[5][DD];  // 0:br 1:bz 2:bnx 3:bnh 4:wout
    __shared__ __align__(16) float Pp[2][NW][16];            // out partials
    __shared__ __align__(16) float outl[MS][OLP];

    const int tid  = threadIdx.x;
    const int n0   = blockIdx.x * MS;
    const int wv   = tid >> 6;       // 0..7 = dim-slice
    const int lane = tid & 63;
    const int ln   = lane & 15;      // C col = seq
    const int q    = lane >> 4;      // C rows q*4..q*4+3 = dims
    const int d4   = wv * 16 + q * 4;
    const float bo = b_out[0];
    const bf16x8* W = (const bf16x8*)Wfrag;

    // 20 persistent weight fragments (80 VGPR); wxn lives in LDS
    bf16x8 wxr[4], wxz[4], whr[4], whz[4], whn[4];
    #pragma unroll
    for (int kk = 0; kk < 4; ++kk) {
        wxr[kk] = W[((0  + wv)*4 + kk)*64 + lane];
        wxz[kk] = W[((8  + wv)*4 + kk)*64 + lane];
        whr[kk] = W[((24 + wv)*4 + kk)*64 + lane];
        whz[kk] = W[((32 + wv)*4 + kk)*64 + lane];
        whn[kk] = W[((40 + wv)*4 + kk)*64 + lane];
    }
    // stage wxn frag region (frags (16..24)*4 = entries 4096..6143) into LDS
    {
        const bf16x8* Wn = W + 16 * 4 * 64;          // 2048 bf16x8 entries
        bf16x8* wl = (bf16x8*)wnl;
        #pragma unroll
        for (int e = 0; e < 4; ++e)
            wl[e * 512 + tid] = Wn[e * 512 + tid];
    }

    // bias / w_out table
    if (tid < DD) {
        const int d = tid;
        bt[0][d] = b_ih[d]        + b_hh[d];
        bt[1][d] = b_ih[DD + d]   + b_hh[DD + d];
        bt[2][d] = b_ih[2*DD + d];
        bt[3][d] = b_hh[2*DD + d];
        bt[4][d] = w_out[d];
    }

    // stage h0 -> xhh[0], x_0 -> xhx[0]  (512 threads x 4 f32 = 16x128)
    const int gn  = tid >> 5;            // seq 0..15
    const int gd4 = (tid & 31) * 4;      // dim 0,4,..,124
    pack4(*(const float4*)&h0[(size_t)(n0 + gn) * DD + gd4], &xhh[0][gn][gd4]);
    const float* xbase = x + ((size_t)(n0 + gn) * LL) * DD + gd4;
    pack4(*(const float4*)xbase, &xhx[0][gn][gd4]);

    // fp32 hidden state: lane=seq(ln), regs = dims d4..d4+3
    float4 hp = *(const float4*)&h0[(size_t)(n0 + ln) * DD + d4];
    float hprev[4] = {hp.x, hp.y, hp.z, hp.w};

    __syncthreads();   // #1: staging done

    for (int t = 0; t < LL; ++t) {
        const int cur = t & 1;
        // prefetch x_{t+1} (latency hides under MFMA + gate phases)
        float4 xa;
        if (t + 1 < LL) xa = *(const float4*)(xbase + (size_t)(t + 1) * DD);

        // accumulators init from bias table (broadcast ds_reads)
        f32x4 ar  = *(const f32x4*)&bt[0][d4];
        f32x4 az  = *(const f32x4*)&bt[1][d4];
        f32x4 anx = *(const f32x4*)&bt[2][d4];
        f32x4 anh = *(const f32x4*)&bt[3][d4];

        const unsigned short* xr = &xhx[cur][ln][0];
        const unsigned short* hr = &xhh[cur][ln][0];
        const bf16x8* wl = (const bf16x8*)wnl;
        __builtin_amdgcn_s_setprio(1);
        #pragma unroll
        for (int kk = 0; kk < 4; ++kk) {           // x-side, K=128
            bf16x8 bx = *(const bf16x8*)(xr + kk*32 + q*8);
            bf16x8 wn = wl[(wv*4 + kk)*64 + lane]; // conflict-free lane-linear
            ar  = MFMA(wxr[kk], bx, ar , 0,0,0);
            az  = MFMA(wxz[kk], bx, az , 0,0,0);
            anx = MFMA(wn,      bx, anx, 0,0,0);
        }
        #pragma unroll
        for (int kk = 0; kk < 4; ++kk) {           // h-side, K=128
            bf16x8 bh = *(const bf16x8*)(hr + kk*32 + q*8);
            ar  = MFMA(whr[kk], bh, ar , 0,0,0);
            az  = MFMA(whz[kk], bh, az , 0,0,0);
            anh = MFMA(whn[kk], bh, anh, 0,0,0);
        }
        __builtin_amdgcn_s_setprio(0);

        // assemble out[t-1] from last step's partials (wave 7 only)
        if (wv == 7 && t >= 1 && lane < 16) {
            float o = bo;
            #pragma unroll
            for (int w = 0; w < NW; ++w) o += Pp[cur ^ 1][w][lane];
            outl[lane][t - 1] = o;
        }

        // gate math (independent chains, r2-proven form)
        float hh_[4];
        #pragma unroll
        for (int i = 0; i < 4; ++i) {
            const float rr = fast_rcp(1.f + __expf(-ar[i]));
            const float zz = fast_rcp(1.f + __expf(-az[i]));
            const float aa = __builtin_fmaf(rr, anh[i], anx[i]);
            const float ee = __expf(-2.f * aa);              // tanh, NaN-free
            const float th = 2.f * fast_rcp(1.f + ee) - 1.f;
            const float hh = __builtin_fmaf(zz, hprev[i] - th, th);
            hprev[i] = hh;
            hh_[i] = hh;
        }
        // h_t write (bf16, vectorized b64)
        {
            union { unsigned u[2]; unsigned long long ull; } hv;
            hv.u[0] = pack2(hh_[0], hh_[1]);
            hv.u[1] = pack2(hh_[2], hh_[3]);
            *(unsigned long long*)&xhh[cur ^ 1][ln][d4] = hv.ull;
        }
        // out partial: f32 dot over this lane's 4 dims, reduce over q
        {
            f32x4 wo = *(const f32x4*)&bt[4][d4];
            float p = hh_[0]*wo[0] + hh_[1]*wo[1] + hh_[2]*wo[2] + hh_[3]*wo[3];
            p += __shfl_xor(p, 16);
            p += __shfl_xor(p, 32);
            if (lane < 16) Pp[cur][wv][lane] = p;
        }
        // stage x_{t+1} into the slot read next iter (WAR-safe: that slot
        // was last read at iter t-1, separated by the iter-(t-1) barrier)
        if (t + 1 < LL) pack4(xa, &xhx[cur ^ 1][gn][gd4]);

        __syncthreads();   // per-step barrier (#2..#33)
    }

    // out[31] from Pp[(LL-1)&1] = Pp[1]
    if (wv == 7 && lane < 16) {
        float o = bo;
        #pragma unroll
        for (int w = 0; w < NW; ++w) o += Pp[1][w][lane];
        outl[lane][LL - 1] = o;
    }
    __syncthreads();       // #34: outl complete

    // coalesced flush: block's 16x32 outputs are contiguous in global
    if (tid < 128) {
        const int row = tid >> 3;
        const int t4  = (tid & 7) * 4;
        float4 v = *(const float4*)&outl[row][t4];
        *(float4*)(out + (size_t)(n0 + row) * LL + t4) = v;
    }
}

extern "C" void kernel_launch(void* const* d_in, const int* in_sizes, int n_in,
                              void* d_out, int out_size, void* d_ws, size_t ws_size,
                              hipStream_t stream) {
    const float* item  = (const float*)d_in[0];
    const float* user  = (const float*)d_in[1];
    const float* W_ih  = (const float*)d_in[2];
    const float* W_hh  = (const float*)d_in[3];
    const float* b_ih  = (const float*)d_in[4];
    const float* b_hh  = (const float*)d_in[5];
    const float* W_out = (const float*)d_in[6];
    const float* b_out = (const float*)d_in[7];
    float* out = (float*)d_out;

    unsigned short* Wfrag = (unsigned short*)d_ws;   // 192 frags * 512 = 98304 bf16

    prep_weights<<<384, 256, 0, stream>>>(W_ih, W_hh, Wfrag);
    gru_mfma<<<NSEQ / MS, NT, 0, stream>>>(item, user, Wfrag,
                                           b_ih, b_hh, W_out, b_out, out);
}

// Round 7
// 218.587 us; speedup vs baseline: 1.5425x; 1.3392x over previous
//
#include <hip/hip_runtime.h>
#include <math.h>

#define DD   128      // hidden dim
#define LL   32       // sequence length
#define MS   32       // sequences per block
#define NT   1024     // 16 waves: 8 consumer + 8 producer
#define NSEQ 8192     // B*S
#define XP   136      // x/h LDS row pitch in ushorts (272 B, 16B-aligned)
#define OLP  36       // outl pitch in floats

// gx passes between producer/consumer as raw C-fragments:
//   [2 slots][48 tiles][64 lanes] x f32x4, tile = (g*8 + pv)*2 + st
// lane-linear 16B/lane -> contiguous 1KB wave access, conflict-free.
#define NFRAG      48
#define FRAGF      (NFRAG * 64 * 4)                   // floats per slot
#define SMEM_XH_X  (2 * FRAGF * 4)                    // 98304
#define SMEM_XH_H  (SMEM_XH_X + 2 * MS * XP * 2)      // +17408
#define SMEM_OUTL  (SMEM_XH_H + 2 * MS * XP * 2)      // +17408
#define SMEM_WOFL  (SMEM_OUTL + MS * OLP * 4)         // +4608
#define SMEM_TOTAL (SMEM_WOFL + 4 * 64 * 8 * 2)       // +4096 = 141824

typedef short bf16x8 __attribute__((ext_vector_type(8)));   // 8 bf16 = 4 VGPRs
typedef float f32x4  __attribute__((ext_vector_type(4)));

// Transposed orientation: A = weights (row = gate-dim), B = x/h (col = seq).
// A-frag and B-frag lane maps are identical, so the same Wfrag bytes and the
// same xh row-reads serve both; C has col(lane&15)=seq, row((lane>>4)*4+i)=dim.
#define MFMA __builtin_amdgcn_mfma_f32_16x16x32_bf16

__device__ __forceinline__ unsigned short f2bf(float f) {
    unsigned u = __float_as_uint(f);
    u += 0x7fffu + ((u >> 16) & 1u);          // round-to-nearest-even
    return (unsigned short)(u >> 16);
}

#if __has_builtin(__builtin_amdgcn_cvt_pk_bf16_f32)
typedef __bf16 bf16x2_t __attribute__((ext_vector_type(2)));
__device__ __forceinline__ unsigned pack2(float a, float b) {
    union { bf16x2_t v; unsigned u; } c;
    c.v = __builtin_amdgcn_cvt_pk_bf16_f32(a, b);
    return c.u;
}
#else
__device__ __forceinline__ unsigned pack2(float a, float b) {
    return (unsigned)f2bf(a) | ((unsigned)f2bf(b) << 16);
}
#endif

__device__ __forceinline__ void pack8(float4 a, float4 b, unsigned short* dst) {
    union { unsigned u[4]; bf16x8 v; } pk;
    pk.u[0] = pack2(a.x, a.y); pk.u[1] = pack2(a.z, a.w);
    pk.u[2] = pack2(b.x, b.y); pk.u[3] = pack2(b.z, b.w);
    *(bf16x8*)dst = pk.v;
}

__device__ __forceinline__ float fast_rcp(float x) {
    return __builtin_amdgcn_rcpf(x);   // v_rcp_f32, ~1 ulp — fine at bf16 output
}

// ---------------------------------------------------------------------------
// Prep: swizzle W_ih / W_hh into per-gate MFMA fragments, bf16. (unchanged)
// Frag index F = ((side*3 + g)*8 + sl)*4 + kk   (side 0=W_ih, 1=W_hh;
// g 0=r,1=z,2=n; sl = 16-dim slice 0..7; kk = K-subtile 0..3).
// Element j of lane (n=lane&15, q=lane>>4):
//   W_side[(g*128 + sl*16 + n) * 128 + (kk*32 + q*8 + j)]
// ---------------------------------------------------------------------------
__global__ void prep_weights(const float* __restrict__ Wih,
                             const float* __restrict__ Whh,
                             unsigned short* __restrict__ Wfrag) {
    int idx  = blockIdx.x * blockDim.x + threadIdx.x;   // 0 .. 98303
    int j    = idx & 7;
    int lane = (idx >> 3) & 63;
    int kk   = (idx >> 9) & 3;
    int sl   = (idx >> 11) & 7;
    int sg   = idx >> 14;            // 0..5 = side*3 + g
    int n = lane & 15, q = lane >> 4;
    int k  = kk * 32 + q * 8 + j;
    int g  = (sg >= 3) ? sg - 3 : sg;
    int gd = g * 128 + sl * 16 + n;
    const float* src = (sg >= 3) ? Whh : Wih;
    Wfrag[idx] = f2bf(src[gd * 128 + k]);
}

// ---------------------------------------------------------------------------
// Wave-specialized GRU, transposed MFMA orientation — the verified r2
// structure (75us, VGPR=64, no spill), with three issue-stream cuts:
//   1. shared-reciprocal r/z sigmoid + bhn folded into ch acc-init
//      (exact math proven in r4: passed, absmax unchanged).
//   2. s_setprio removed (T5 is null-to-negative on lockstep barriers, m190).
//   3. #pragma unroll 2 on the t-loops: t&1 parity folds to compile-time,
//      deleting the per-iteration address-select chains.
// ---------------------------------------------------------------------------
__global__ __launch_bounds__(NT, 4) void gru_mfma(
    const float* __restrict__ x,      // [8192][32][128]
    const float* __restrict__ h0,     // [8192][128]
    const unsigned short* __restrict__ Wfrag,
    const float* __restrict__ b_ih,   // [384]
    const float* __restrict__ b_hh,   // [384]
    const float* __restrict__ w_out,  // [128]
    const float* __restrict__ b_out,  // [1]
    float* __restrict__ out)          // [8192][32]
{
    extern __shared__ char smem[];
    float*          gxf  = (float*)(smem);                       // [2][48][64][4]
    unsigned short* xhx  = (unsigned short*)(smem + SMEM_XH_X);  // [2][MS][XP]
    unsigned short* xhh  = (unsigned short*)(smem + SMEM_XH_H);  // [2][MS][XP]
    float*          outl = (float*)(smem + SMEM_OUTL);           // [MS][OLP]
    unsigned short* wofl = (unsigned short*)(smem + SMEM_WOFL);  // [2048]

    const int tid  = threadIdx.x;
    const int n0   = blockIdx.x * MS;
    const int wv   = tid >> 6;       // 0..15
    const int lane = tid & 63;
    const int ln   = lane & 15;      // C col = seq within tile
    const int q    = lane >> 4;      // C rows q*4..q*4+3 = gate-dims
    const bf16x8* W = (const bf16x8*)Wfrag;

    if (wv < 8) {
        // ================= CONSUMER =================
        const int d4 = wv * 16 + q * 4;            // first of this lane's 4 dims
        const f32x4 bhn4 = *(const f32x4*)&b_hh[2*DD + d4];

        bf16x8 whr[4], whz[4], whn[4];             // A-operands (W_hh slices)
        #pragma unroll
        for (int kk = 0; kk < 4; ++kk) {
            whr[kk] = W[((24 + wv)*4 + kk)*64 + lane];
            whz[kk] = W[((32 + wv)*4 + kk)*64 + lane];
            whn[kk] = W[((40 + wv)*4 + kk)*64 + lane];
        }

        // stage W_out A-fragment (row 0 = w_out, rows 1..15 = 0)
        #pragma unroll
        for (int e = 0; e < 4; ++e) {
            int idx = tid * 4 + e;              // 0..2047
            int j   = idx & 7;
            int l2  = (idx >> 3) & 63;
            int kk  = idx >> 9;                 // 0..3
            int n2 = l2 & 15, q2 = l2 >> 4;
            wofl[idx] = (n2 == 0) ? f2bf(w_out[kk * 32 + q2 * 8 + j])
                                  : (unsigned short)0;
        }
        // stage h0 (bf16) into xhh slot 0
        {
            const int gn = tid >> 4, gd8 = (tid & 15) * 8;
            const float* hb = h0 + (size_t)(n0 + gn) * DD + gd8;
            pack8(*(const float4*)hb, *(const float4*)(hb + 4),
                  &xhh[gn * XP + gd8]);
        }
        // fp32 hidden state: lane=seq(ln), regs = dims d4..d4+3, per seq-tile st
        float4 hp0 = *(const float4*)&h0[(size_t)(n0 + ln) * DD + d4];
        float4 hp1 = *(const float4*)&h0[(size_t)(n0 + 16 + ln) * DD + d4];
        float hprev[8] = {hp0.x, hp0.y, hp0.z, hp0.w,
                          hp1.x, hp1.y, hp1.z, hp1.w};

        __syncthreads();   // #1: staging done
        __syncthreads();   // #2: gx[0] ready

        #pragma unroll 2
        for (int t = 0; t < LL; ++t) {
            const int sl_ = t & 1;
            const float* gf = gxf + sl_ * FRAGF;
            f32x4 cr[2], cz[2], ch[2];
            #pragma unroll
            for (int st = 0; st < 2; ++st) {
                cr[st] = *(const f32x4*)&gf[(((0*8 + wv)*2 + st)*64 + lane)*4];
                cz[st] = *(const f32x4*)&gf[(((1*8 + wv)*2 + st)*64 + lane)*4];
                ch[st] = bhn4;                 // b_hn folded into acc init
            }
            const unsigned short* hr0 = xhh + sl_*MS*XP + ln*XP;
            const unsigned short* hr1 = hr0 + 16*XP;
            #pragma unroll
            for (int kk = 0; kk < 4; ++kk) {
                bf16x8 b0 = *(const bf16x8*)(hr0 + kk*32 + q*8);
                bf16x8 b1 = *(const bf16x8*)(hr1 + kk*32 + q*8);
                cr[0] = MFMA(whr[kk], b0, cr[0], 0,0,0);
                cr[1] = MFMA(whr[kk], b1, cr[1], 0,0,0);
                cz[0] = MFMA(whz[kk], b0, cz[0], 0,0,0);
                cz[1] = MFMA(whz[kk], b1, cz[1], 0,0,0);
                ch[0] = MFMA(whn[kk], b0, ch[0], 0,0,0);
                ch[1] = MFMA(whn[kk], b1, ch[1], 0,0,0);
            }
            // n-gate x-side preacts read late (short live range)
            f32x4 gnx[2];
            #pragma unroll
            for (int st = 0; st < 2; ++st)
                gnx[st] = *(const f32x4*)&gf[(((2*8 + wv)*2 + st)*64 + lane)*4];

            unsigned short* hw = xhh + (sl_ ^ 1)*MS*XP;
            #pragma unroll
            for (int st = 0; st < 2; ++st) {
                float hh_[4];
                #pragma unroll
                for (int i = 0; i < 4; ++i) {
                    // shared-reciprocal double sigmoid (r4-proven numerics):
                    // 3 exp + 2 rcp per element incl. tanh; e-clamp kills 0*inf
                    const float e1 = fminf(__expf(-cr[st][i]), 1e18f);
                    const float e2 = fminf(__expf(-cz[st][i]), 1e18f);
                    const float p1 = 1.f + e1, p2 = 1.f + e2;
                    const float R  = fast_rcp(p1 * p2);
                    const float rr = R * p2;
                    const float zz = R * p1;
                    const float aa = __builtin_fmaf(rr, ch[st][i], gnx[st][i]);
                    // tanh(aa) = 2/(1+exp(-2a)) - 1 : NaN-free
                    const float ee = __expf(-2.f * aa);
                    const float th = 2.f * fast_rcp(1.f + ee) - 1.f;
                    const float hh = __builtin_fmaf(zz, hprev[st*4+i] - th, th);
                    hprev[st*4+i] = hh;
                    hh_[i] = hh;
                }
                union { unsigned u[2]; unsigned long long ull; } hv;
                hv.u[0] = pack2(hh_[0], hh_[1]);
                hv.u[1] = pack2(hh_[2], hh_[3]);
                *(unsigned long long*)&hw[(st*16 + ln)*XP + d4] = hv.ull;
            }
            __syncthreads();   // #3..#34
        }
        __syncthreads();       // #35: outl col 31 ready

        // coalesced flush: block's 32x32 outputs are contiguous in global
        if (tid < 256) {
            const int row = tid >> 3;
            const int t4  = (tid & 7) * 4;
            float4 v = *(const float4*)&outl[row * OLP + t4];
            *(float4*)(out + (size_t)(n0 + row) * LL + t4) = v;
        }
    } else {
        // ================= PRODUCER =================
        const int pv = wv - 8;
        const int d4 = pv * 16 + q * 4;
        // bake b_ih + b_hh into r,z; b_ih only into n (b_hh n-side is consumer's)
        f32x4 br4, bz4, bn4;
        {
            f32x4 a0 = *(const f32x4*)&b_ih[d4];
            f32x4 a1 = *(const f32x4*)&b_hh[d4];
            br4 = a0 + a1;
            a0 = *(const f32x4*)&b_ih[DD + d4];
            a1 = *(const f32x4*)&b_hh[DD + d4];
            bz4 = a0 + a1;
            bn4 = *(const f32x4*)&b_ih[2*DD + d4];
        }
        const float bo = b_out[0];

        bf16x8 wxr[4], wxz[4], wxn[4];             // A-operands (W_ih slices)
        #pragma unroll
        for (int kk = 0; kk < 4; ++kk) {
            wxr[kk] = W[((0  + pv)*4 + kk)*64 + lane];
            wxz[kk] = W[((8  + pv)*4 + kk)*64 + lane];
            wxn[kk] = W[((16 + pv)*4 + kk)*64 + lane];
        }

        const int pt  = tid & 511;
        const int gn  = pt >> 4;             // staging: seq 0..31
        const int gd8 = (pt & 15) * 8;       // staging: dim 0,8,..,120
        const float* xbase = x + ((size_t)(n0 + gn) * LL) * DD + gd8;

        // prologue: stage x_0 -> slot 0, x_1 -> slot 1
        pack8(*(const float4*)(xbase), *(const float4*)(xbase + 4),
              &xhx[gn * XP + gd8]);
        pack8(*(const float4*)(xbase + DD), *(const float4*)(xbase + DD + 4),
              &xhx[MS*XP + gn * XP + gd8]);

        __syncthreads();   // #1: staging done

#define GX_STEP(TT)                                                            \
        {                                                                      \
            const int sr = (TT) & 1;                                           \
            const unsigned short* xr0 = xhx + sr*MS*XP + ln*XP;                \
            const unsigned short* xr1 = xr0 + 16*XP;                           \
            f32x4 ar[2], az[2], an[2];                                         \
            ar[0] = br4; ar[1] = br4;                                          \
            az[0] = bz4; az[1] = bz4;                                          \
            an[0] = bn4; an[1] = bn4;                                          \
            _Pragma("unroll")                                                  \
            for (int kk = 0; kk < 4; ++kk) {                                   \
                bf16x8 b0 = *(const bf16x8*)(xr0 + kk*32 + q*8);               \
                bf16x8 b1 = *(const bf16x8*)(xr1 + kk*32 + q*8);               \
                ar[0] = MFMA(wxr[kk], b0, ar[0], 0,0,0);                       \
                ar[1] = MFMA(wxr[kk], b1, ar[1], 0,0,0);                       \
                az[0] = MFMA(wxz[kk], b0, az[0], 0,0,0);                       \
                az[1] = MFMA(wxz[kk], b1, az[1], 0,0,0);                       \
                an[0] = MFMA(wxn[kk], b0, an[0], 0,0,0);                       \
                an[1] = MFMA(wxn[kk], b1, an[1], 0,0,0);                       \
            }                                                                  \
            float* gw = gxf + sr * FRAGF;                                      \
            _Pragma("unroll")                                                  \
            for (int st = 0; st < 2; ++st) {                                   \
                *(f32x4*)&gw[(((0*8 + pv)*2 + st)*64 + lane)*4] = ar[st];      \
                *(f32x4*)&gw[(((1*8 + pv)*2 + st)*64 + lane)*4] = az[st];      \
                *(f32x4*)&gw[(((2*8 + pv)*2 + st)*64 + lane)*4] = an[st];      \
            }                                                                  \
        }

        // prologue: gx[0] from x_0
        GX_STEP(0)
        __syncthreads();   // #2: gx[0] ready

        #pragma unroll 2
        for (int t = 0; t < LL; ++t) {
            // issue x_{t+2} loads early (latency hides under gx GEMM)
            float4 sa, sb;
            const int ts = t + 2;
            if (ts < LL) {
                sa = *(const float4*)(xbase + (size_t)ts * DD);
                sb = *(const float4*)(xbase + (size_t)ts * DD + 4);
            }
            // gx[t+1] from x_{t+1}
            if (t + 1 < LL) GX_STEP(t + 1)

            // out[t-1] = h_{t-1} . w_out  (waves pv=0/1; seq-tile = pv)
            if (pv < 2 && t >= 1) {
                f32x4 c4 = (f32x4){bo, bo, bo, bo};
                const unsigned short* hrw = xhh + (t & 1)*MS*XP + (pv*16 + ln)*XP;
                #pragma unroll
                for (int kk = 0; kk < 4; ++kk) {
                    bf16x8 a = *(const bf16x8*)&wofl[(kk*64 + lane)*8];
                    bf16x8 b = *(const bf16x8*)(hrw + kk*32 + q*8);
                    c4 = MFMA(a, b, c4, 0,0,0);
                }
                if (q == 0)                       // C row 0 lives in q=0, i=0
                    outl[(pv*16 + ln)*OLP + (t - 1)] = c4[0];
            }
            // late half of staging: pack + LDS write of x_{t+2}
            if (ts < LL)
                pack8(sa, sb, &xhx[(t & 1)*MS*XP + gn * XP + gd8]);

            __syncthreads();   // #3..#34
        }

        // final output column: out[31] = h_31 . w_out (h_31 in xhh slot 0)
        if (pv < 2) {
            f32x4 c4 = (f32x4){bo, bo, bo, bo};
            const unsigned short* hrw = xhh + (pv*16 + ln)*XP;
            #pragma unroll
            for (int kk = 0; kk < 4; ++kk) {
                bf16x8 a = *(const bf16x8*)&wofl[(kk*64 + lane)*8];
                bf16x8 b = *(const bf16x8*)(hrw + kk*32 + q*8);
                c4 = MFMA(a, b, c4, 0,0,0);
            }
            if (q == 0)
                outl[(pv*16 + ln)*OLP + (LL - 1)] = c4[0];
        }
        __syncthreads();       // #35
#undef GX_STEP
    }
}

extern "C" void kernel_launch(void* const* d_in, const int* in_sizes, int n_in,
                              void* d_out, int out_size, void* d_ws, size_t ws_size,
                              hipStream_t stream) {
    const float* item  = (const float*)d_in[0];
    const float* user  = (const float*)d_in[1];
    const float* W_ih  = (const float*)d_in[2];
    const float* W_hh  = (const float*)d_in[3];
    const float* b_ih  = (const float*)d_in[4];
    const float* b_hh  = (const float*)d_in[5];
    const float* W_out = (const float*)d_in[6];
    const float* b_out = (const float*)d_in[7];
    float* out = (float*)d_out;

    unsigned short* Wfrag = (unsigned short*)d_ws;   // 192 frags * 512 = 98304 bf16

    static bool smem_cfg = false;
    if (!smem_cfg) {
        hipFuncSetAttribute((const void*)gru_mfma,
                            hipFuncAttributeMaxDynamicSharedMemorySize,
                            SMEM_TOTAL);
        smem_cfg = true;
    }

    prep_weights<<<384, 256, 0, stream>>>(W_ih, W_hh, Wfrag);
    gru_mfma<<<NSEQ / MS, NT, SMEM_TOTAL, stream>>>(item, user, Wfrag,
                                                    b_ih, b_hh, W_out, b_out, out);
}